// Round 1
// baseline (9901.514 us; speedup 1.0000x reference)
//
#include <hip/hip_runtime.h>
#include <hip/hip_fp16.h>
#include <cstddef>

#define T_LEN 4096
#define HID 150
#define G4 600
#define NC 300

// raw barrier: waits LDS ops only, leaves global loads/stores in flight
__device__ __forceinline__ void barrier_lgkm() {
  asm volatile("s_waitcnt lgkmcnt(0)\n\ts_barrier" ::: "memory");
}

__device__ __forceinline__ float fsig(float x) {
  return __builtin_amdgcn_rcpf(1.f + __expf(-x));
}
__device__ __forceinline__ float ftanh(float x) {
  float ax = fabsf(x);
  float e = __expf(2.f * ax);
  float t = 1.f - 2.f * __builtin_amdgcn_rcpf(e + 1.f);
  return copysignf(t, x);
}

// ---------------- LSTM scan: 4 chains (net x dir), one block each --------------
// block 512: tid = kt*128 + jt ; thread owns gates j = jt+128q (q<5), k in [kt*40, kt*40+40)
constexpr int SC_KT = 4, SC_KC = 40, SC_NQ = 5;

__global__ __launch_bounds__(512, 2) void lstm_scan(
    const float* __restrict__ whh_solv, const float* __restrict__ whh_solu,
    const float* __restrict__ xg_base,
    float* __restrict__ out_solv, float* __restrict__ out_solu, int layer)
{
  __shared__ __align__(16) float h_s[SC_KT * SC_KC];   // 160 floats, zeros beyond 150
  __shared__ float pbuf[640][SC_KT + 1];               // +1 pad: conflict-free
  const int c = blockIdx.x;
  const int net = c >> 1, dir = c & 1;
  const float* Whh = (net ? whh_solu : whh_solv) + (size_t)(layer * 2 + dir) * (G4 * HID);
  const float* xg = xg_base + (size_t)c * T_LEN * G4;
  float* out = (net ? out_solu : out_solv) + dir * HID;  // row stride NC
  const int tid = threadIdx.x;
  const int kt = tid >> 7, jt = tid & 127;
  const int k0 = kt * SC_KC;

  // weights -> registers (one-time)
  float w[SC_NQ][SC_KC];
#pragma unroll
  for (int q = 0; q < SC_NQ; q++) {
    const int j = jt + 128 * q;
    const bool jv = (j < G4);
#pragma unroll
    for (int i = 0; i < SC_KC; i++) {
      const int k = k0 + i;
      w[q][i] = (jv && k < HID) ? Whh[(size_t)j * HID + k] : 0.f;
    }
  }
  if (tid < SC_KT * SC_KC) h_s[tid] = 0.f;
  float cst = 0.f;
  float xr0 = 0.f, xr1 = 0.f, xr2 = 0.f, xr3 = 0.f;
  if (tid < HID) {
    const int t0 = dir ? (T_LEN - 1) : 0;
    const float* xgr = xg + (size_t)t0 * G4 + tid;
    xr0 = xgr[0]; xr1 = xgr[HID]; xr2 = xgr[2 * HID]; xr3 = xgr[3 * HID];
  }
  barrier_lgkm();

  for (int s = 0; s < T_LEN; s++) {
    const int t = dir ? (T_LEN - 1 - s) : s;
    float acc[SC_NQ] = {0.f, 0.f, 0.f, 0.f, 0.f};
#pragma unroll
    for (int i = 0; i < SC_KC; i += 4) {
      const float4 hv = *(const float4*)&h_s[k0 + i];   // broadcast read
#pragma unroll
      for (int q = 0; q < SC_NQ; q++)
        acc[q] += w[q][i] * hv.x + w[q][i + 1] * hv.y + w[q][i + 2] * hv.z + w[q][i + 3] * hv.w;
    }
#pragma unroll
    for (int q = 0; q < SC_NQ; q++) pbuf[jt + 128 * q][kt] = acc[q];
    barrier_lgkm();
    if (tid < HID) {
      const int n = tid;
      float gi = xr0, gf = xr1, gg = xr2, go = xr3;
#pragma unroll
      for (int kk = 0; kk < SC_KT; kk++) {
        gi += pbuf[n][kk];
        gf += pbuf[HID + n][kk];
        gg += pbuf[2 * HID + n][kk];
        go += pbuf[3 * HID + n][kk];
      }
      if (s + 1 < T_LEN) {  // prefetch next xg row (consumed next step; barrier leaves it in flight)
        const int tn = dir ? (T_LEN - 2 - s) : (s + 1);
        const float* xgr = xg + (size_t)tn * G4 + n;
        xr0 = xgr[0]; xr1 = xgr[HID]; xr2 = xgr[2 * HID]; xr3 = xgr[3 * HID];
      }
      const float iv = fsig(gi), fv = fsig(gf), gv = ftanh(gg), ov = fsig(go);
      cst = fv * cst + iv * gv;
      const float hv = ov * ftanh(cst);
      h_s[n] = hv;
      out[(size_t)t * NC + n] = hv;
    }
    barrier_lgkm();
  }
}

// ---------------- generic tiled fp32 GEMM -------------------------------------
// MODE: 0 = NT (C=A*B^T), 1 = NN, 2 = TN.  EPI: 0 = float C (+bias e0[n]+e1[n] if e0),
// 1 = half C = exp(acc - e0[m]) * e1[m]
__device__ __forceinline__ float to_f(float v) { return v; }
__device__ __forceinline__ float to_f(__half v) { return __half2float(v); }

template <int MODE, typename TA, int EPI>
__global__ void gemm_k(const TA* __restrict__ A, const float* __restrict__ B,
                       void* __restrict__ Cv, int M, int N, int K,
                       int lda, int ldb, int ldc,
                       const float* __restrict__ e0, const float* __restrict__ e1)
{
  __shared__ __align__(16) float As[16][64];
  __shared__ __align__(16) float Bs[16][64];
  const int tid = threadIdx.x;
  const int tx = tid & 15, ty = tid >> 4;
  const int m0 = blockIdx.y * 64, n0 = blockIdx.x * 64;
  float acc[4][4] = {};
  for (int kc = 0; kc < K; kc += 16) {
#pragma unroll
    for (int j = 0; j < 4; j++) {
      const int li = tid * 4 + j;
      int ml, kl;
      if (MODE == 2) { ml = li & 63; kl = li >> 6; }
      else           { ml = li >> 4; kl = li & 15; }
      const int m = m0 + ml, k = kc + kl;
      float v = 0.f;
      if (m < M && k < K)
        v = to_f(MODE == 2 ? A[(size_t)k * lda + m] : A[(size_t)m * lda + k]);
      As[kl][ml] = v;
    }
#pragma unroll
    for (int j = 0; j < 4; j++) {
      const int li = tid * 4 + j;
      int nl, kl;
      if (MODE == 0) { nl = li >> 4; kl = li & 15; }
      else           { nl = li & 63; kl = li >> 6; }
      const int n = n0 + nl, k = kc + kl;
      float v = 0.f;
      if (n < N && k < K)
        v = (MODE == 0) ? B[(size_t)n * ldb + k] : B[(size_t)k * ldb + n];
      Bs[kl][nl] = v;
    }
    __syncthreads();
#pragma unroll
    for (int kl = 0; kl < 16; kl++) {
      const float4 av = *(const float4*)&As[kl][ty * 4];
      const float4 bv = *(const float4*)&Bs[kl][tx * 4];
      const float aa[4] = {av.x, av.y, av.z, av.w};
      const float bb[4] = {bv.x, bv.y, bv.z, bv.w};
#pragma unroll
      for (int i = 0; i < 4; i++)
#pragma unroll
        for (int jj = 0; jj < 4; jj++)
          acc[i][jj] += aa[i] * bb[jj];
    }
    __syncthreads();
  }
#pragma unroll
  for (int i = 0; i < 4; i++) {
    const int m = m0 + ty * 4 + i;
    if (m >= M) continue;
#pragma unroll
    for (int j = 0; j < 4; j++) {
      const int n = n0 + tx * 4 + j;
      if (n >= N) continue;
      if (EPI == 0) {
        float v = acc[i][j];
        if (e0) v += e0[n] + e1[n];
        ((float*)Cv)[(size_t)m * ldc + n] = v;
      } else {
        const float v = __expf(acc[i][j] - e0[m]) * e1[m];
        ((__half*)Cv)[(size_t)m * ldc + n] = __float2half(v);
      }
    }
  }
}

// ------------- attention softmax stats (never materializes S) -----------------
// grid (8 g-chunks, 64 h-blocks), block 256; writes partial (m,l) per row per chunk
__global__ void attn_stats(const float* __restrict__ Hm, const float* __restrict__ Gm,
                           float* __restrict__ pm, float* __restrict__ pl)
{
  __shared__ __align__(16) float As[16][64];
  __shared__ __align__(16) float Bs[16][64];
  const int tid = threadIdx.x;
  const int tx = tid & 15, ty = tid >> 4;
  const int m0 = blockIdx.y * 64;
  float rm[4], rl[4];
#pragma unroll
  for (int i = 0; i < 4; i++) { rm[i] = -3e38f; rl[i] = 0.f; }
  for (int nt = 0; nt < 8; nt++) {
    const int n0 = (blockIdx.x * 8 + nt) * 64;
    float acc[4][4] = {};
    for (int kc = 0; kc < NC; kc += 16) {
#pragma unroll
      for (int j = 0; j < 4; j++) {
        const int li = tid * 4 + j;
        const int ml = li >> 4, kl = li & 15;
        const int k = kc + kl;
        As[kl][ml] = (k < NC) ? Hm[(size_t)(m0 + ml) * NC + k] : 0.f;
        Bs[kl][ml] = (k < NC) ? Gm[(size_t)(n0 + ml) * NC + k] : 0.f;
      }
      __syncthreads();
#pragma unroll
      for (int kl = 0; kl < 16; kl++) {
        const float4 av = *(const float4*)&As[kl][ty * 4];
        const float4 bv = *(const float4*)&Bs[kl][tx * 4];
        const float aa[4] = {av.x, av.y, av.z, av.w};
        const float bb[4] = {bv.x, bv.y, bv.z, bv.w};
#pragma unroll
        for (int i = 0; i < 4; i++)
#pragma unroll
          for (int jj = 0; jj < 4; jj++)
            acc[i][jj] += aa[i] * bb[jj];
      }
      __syncthreads();
    }
#pragma unroll
    for (int i = 0; i < 4; i++) {
      const float mx = fmaxf(fmaxf(acc[i][0], acc[i][1]), fmaxf(acc[i][2], acc[i][3]));
      const float nm = fmaxf(rm[i], mx);
      const float s = __expf(acc[i][0] - nm) + __expf(acc[i][1] - nm) +
                      __expf(acc[i][2] - nm) + __expf(acc[i][3] - nm);
      rl[i] = rl[i] * __expf(rm[i] - nm) + s;
      rm[i] = nm;
    }
  }
  __syncthreads();
#pragma unroll
  for (int i = 0; i < 4; i++) { As[tx][ty * 4 + i] = rm[i]; Bs[tx][ty * 4 + i] = rl[i]; }
  __syncthreads();
  if (tid < 64) {
    float m = As[0][tid], l = Bs[0][tid];
#pragma unroll
    for (int c2 = 1; c2 < 16; c2++) {
      const float m2 = As[c2][tid], l2 = Bs[c2][tid];
      const float nm = fmaxf(m, m2);
      l = l * __expf(m - nm) + l2 * __expf(m2 - nm);
      m = nm;
    }
    pm[(size_t)(m0 + tid) * 8 + blockIdx.x] = m;
    pl[(size_t)(m0 + tid) * 8 + blockIdx.x] = l;
  }
}

__global__ void stats_combine(const float* __restrict__ pm, const float* __restrict__ pl,
                              float* __restrict__ mrow, float* __restrict__ invl)
{
  const int r = blockIdx.x * 256 + threadIdx.x;
  float m = -3e38f;
#pragma unroll
  for (int c2 = 0; c2 < 8; c2++) m = fmaxf(m, pm[r * 8 + c2]);
  float l = 0.f;
#pragma unroll
  for (int c2 = 0; c2 < 8; c2++) l += pl[r * 8 + c2] * __expf(pm[r * 8 + c2] - m);
  mrow[r] = m;
  invl[r] = 1.f / l;
}

// ---------------- tail ---------------------------------------------------------
__global__ void zero_inp(float* __restrict__ inp) {
  if (threadIdx.x < 600) inp[threadIdx.x] = 0.f;
}

__global__ void reduce_uv(const float* __restrict__ X, const float* __restrict__ Yp,
                          float* __restrict__ inp, int off)
{
  const int j = threadIdx.x;
  if (j >= NC) return;
  const int r0 = blockIdx.x * 128;
  float s = 0.f;
  for (int r = r0; r < r0 + 128; r++)
    s += fmaxf(X[(size_t)r * NC + j], Yp[(size_t)r * NC + j]);
  atomicAdd(&inp[off + j], s);
}

__global__ void fc1_k(const float* __restrict__ w1, const float* __restrict__ b1,
                      const float* __restrict__ inp, float* __restrict__ x)
{
  const int r = blockIdx.x * 256 + threadIdx.x;
  if (r >= 2000) return;
  float s = b1[r];
  const float* wr = w1 + (size_t)r * 600;
  for (int k = 0; k < 600; k++) s += wr[k] * inp[k];
  x[r] = fmaxf(s, 0.f);
}

__global__ void fc2_k(const float* __restrict__ x, const float* __restrict__ w2,
                      const float* __restrict__ b2, float* __restrict__ outp)
{
  const int tid = threadIdx.x;
  float s = 0.f;
  for (int i = tid; i < 2000; i += 256) s += x[i] * w2[i];
#pragma unroll
  for (int off = 32; off > 0; off >>= 1) s += __shfl_down(s, off);
  __shared__ float red[4];
  if ((tid & 63) == 0) red[tid >> 6] = s;
  __syncthreads();
  if (tid == 0) outp[0] = red[0] + red[1] + red[2] + red[3] + b2[0];
}

// ---------------- launch --------------------------------------------------------
extern "C" void kernel_launch(void* const* d_in, const int* in_sizes, int n_in,
                              void* d_out, int out_size, void* d_ws, size_t ws_size,
                              hipStream_t stream)
{
  const float* in_solv  = (const float*)d_in[0];
  const float* in_solu  = (const float*)d_in[1];
  const float* solv_Wih = (const float*)d_in[2];
  const float* solv_Whh = (const float*)d_in[3];
  const float* solv_bih = (const float*)d_in[4];
  const float* solv_bhh = (const float*)d_in[5];
  const float* solu_Wih = (const float*)d_in[6];
  const float* solu_Whh = (const float*)d_in[7];
  const float* solu_bih = (const float*)d_in[8];
  const float* solu_bhh = (const float*)d_in[9];
  const float* fc1_w = (const float*)d_in[10];
  const float* fc1_b = (const float*)d_in[11];
  const float* fc2_w = (const float*)d_in[12];
  const float* fc2_b = (const float*)d_in[13];
  float* outp = (float*)d_out;
  float* ws = (float*)d_ws;

  // workspace layout (float offsets); AH(half) aliases dead xg region. total ~69 MB
  constexpr size_t off_P   = 0;
  constexpr size_t off_Q   = 1228800;
  constexpr size_t off_inp = 2457600;
  constexpr size_t off_x   = 2458240;
  constexpr size_t off_pm  = 2460288;
  constexpr size_t off_pl  = 2493056;
  constexpr size_t off_mr  = 2525824;
  constexpr size_t off_il  = 2529920;
  constexpr size_t off_xg  = 2534016;
  constexpr size_t off_L0  = off_xg + (size_t)4 * 2457600;
  constexpr size_t off_HG  = off_L0 + (size_t)2 * 1228800;

  float* xg  = ws + off_xg;
  float* L0v = ws + off_L0;
  float* L0u = L0v + 1228800;
  float* Hb  = ws + off_HG;
  float* Gb  = Hb + 1228800;
  float* Pb  = ws + off_P;
  float* Qb  = ws + off_Q;
  float* inp = ws + off_inp;
  float* xf  = ws + off_x;
  float* pm  = ws + off_pm;
  float* pl  = ws + off_pl;
  float* mr  = ws + off_mr;
  float* il  = ws + off_il;
  __half* AH = (__half*)(ws + off_xg);

  // layer 0: xg = X @ Wih^T + (bih+bhh), 4 chains
  for (int c = 0; c < 4; c++) {
    const int net = c >> 1, d = c & 1;
    const float* X   = net ? in_solu : in_solv;
    const float* Wih = (net ? solu_Wih : solv_Wih) + (size_t)d * (600 * 300);
    const float* bi  = (net ? solu_bih : solv_bih) + (size_t)d * 600;
    const float* bh  = (net ? solu_bhh : solv_bhh) + (size_t)d * 600;
    gemm_k<0, float, 0><<<dim3(10, 64), 256, 0, stream>>>(
        X, Wih, (void*)(xg + (size_t)c * 2457600), 4096, 600, 300, 300, 300, 600, bi, bh);
  }
  lstm_scan<<<4, 512, 0, stream>>>(solv_Whh, solu_Whh, xg, L0v, L0u, 0);

  // layer 1
  for (int c = 0; c < 4; c++) {
    const int net = c >> 1, d = c & 1;
    const float* X   = net ? L0u : L0v;
    const float* Wih = (net ? solu_Wih : solv_Wih) + (size_t)(2 + d) * (600 * 300);
    const float* bi  = (net ? solu_bih : solv_bih) + (size_t)(2 + d) * 600;
    const float* bh  = (net ? solu_bhh : solv_bhh) + (size_t)(2 + d) * 600;
    gemm_k<0, float, 0><<<dim3(10, 64), 256, 0, stream>>>(
        X, Wih, (void*)(xg + (size_t)c * 2457600), 4096, 600, 300, 300, 300, 600, bi, bh);
  }
  lstm_scan<<<4, 512, 0, stream>>>(solv_Whh, solu_Whh, xg, Hb, Gb, 1);

  // attention
  attn_stats<<<dim3(8, 64), 256, 0, stream>>>(Hb, Gb, pm, pl);
  stats_combine<<<16, 256, 0, stream>>>(pm, pl, mr, il);
  gemm_k<0, float, 1><<<dim3(64, 64), 256, 0, stream>>>(
      Hb, Gb, (void*)AH, 4096, 4096, 300, 300, 300, 4096, mr, il);
  gemm_k<1, __half, 0><<<dim3(5, 64), 256, 0, stream>>>(
      AH, Gb, (void*)Pb, 4096, 300, 4096, 4096, 300, 300, nullptr, nullptr);
  gemm_k<2, __half, 0><<<dim3(5, 64), 256, 0, stream>>>(
      AH, Hb, (void*)Qb, 4096, 300, 4096, 4096, 300, 300, nullptr, nullptr);

  // tail
  zero_inp<<<1, 640, 0, stream>>>(inp);
  reduce_uv<<<32, 320, 0, stream>>>(Hb, Pb, inp, 0);
  reduce_uv<<<32, 320, 0, stream>>>(Gb, Qb, inp, 300);
  fc1_k<<<8, 256, 0, stream>>>(fc1_w, fc1_b, inp, xf);
  fc2_k<<<1, 256, 0, stream>>>(xf, fc2_w, fc2_b, outp);
}